// Round 1
// baseline (1726.340 us; speedup 1.0000x reference)
//
#include <hip/hip_runtime.h>

// LightGCN on MI355X.
// Nodes: 500k users + 300k items = 800k, DIM=64 f32, 1.25M edges, 3 layers.
// out = (h0 + h1 + h2 + h3)/4 where h_{k+1}[v] = dn[v] * sum_{e:dst=v} sn[src]*h_k[src].

static constexpr int NU = 500000;    // users
static constexpr int NI = 300000;    // items
static constexpr int NN = NU + NI;   // 800000 nodes
static constexpr int NE = 1250000;   // edges
static constexpr int DIM = 64;

// ---- degree accumulation (float atomics; counts exact < 2^24) ----
__global__ void deg_kernel(const int* __restrict__ src, const int* __restrict__ dst,
                           float* __restrict__ dego, float* __restrict__ degi) {
    int e = blockIdx.x * blockDim.x + threadIdx.x;
    if (e < NE) {
        atomicAdd(&dego[src[e]], 1.0f);
        atomicAdd(&degi[dst[e]], 1.0f);
    }
}

// ---- turn degrees into norms in-place; comb = sn*dn for inner layers ----
__global__ void norm_kernel(float* __restrict__ sn, float* __restrict__ dn,
                            float* __restrict__ comb) {
    int i = blockIdx.x * blockDim.x + threadIdx.x;
    if (i < NN) {
        float a = rsqrtf(fmaxf(sn[i], 1.0f));
        float b = rsqrtf(fmaxf(dn[i], 1.0f));
        sn[i] = a;
        dn[i] = b;
        comb[i] = a * b;
    }
}

// ---- layer-1 edge scatter: reads h0 straight from the two input arrays ----
// one wave = one edge; lane d = dim d -> coalesced 256B gather + 256B atomic line
__global__ void edge1_kernel(const float* __restrict__ ue, const float* __restrict__ ie,
                             const int* __restrict__ src, const int* __restrict__ dst,
                             const float* __restrict__ sn, float* __restrict__ agg) {
    int t = blockIdx.x * blockDim.x + threadIdx.x;
    int e = t >> 6;
    if (e >= NE) return;
    int d = t & 63;
    int s = src[e];          // wave-uniform broadcast load
    int q = dst[e];
    float v = (s < NU) ? ue[(size_t)s * DIM + d]
                       : ie[(size_t)(s - NU) * DIM + d];
    v *= sn[s];
    atomicAdd(&agg[(size_t)q * DIM + d], v);
}

// ---- inner-layer edge scatter: h_k = agg_prev * dn folded into w = sn*dn ----
__global__ void edge_kernel(const float* __restrict__ h, const int* __restrict__ src,
                            const int* __restrict__ dst, const float* __restrict__ w,
                            float* __restrict__ agg) {
    int t = blockIdx.x * blockDim.x + threadIdx.x;
    int e = t >> 6;
    if (e >= NE) return;
    int d = t & 63;
    int s = src[e];
    int q = dst[e];
    float v = h[(size_t)s * DIM + d] * w[s];
    atomicAdd(&agg[(size_t)q * DIM + d], v);
}

// ---- accumulate pass, float4-vectorized: 16 float4 per node ----
// MODE 0: acc = h0 + agg*dn      (init from inputs)
// MODE 1: acc += agg*dn
// MODE 2: acc = (acc + agg*dn) * 0.25f   (final average)
template <int MODE>
__global__ void p_kernel(const float* __restrict__ ue, const float* __restrict__ ie,
                         const float* __restrict__ agg, const float* __restrict__ dn,
                         float* __restrict__ acc) {
    int t = blockIdx.x * blockDim.x + threadIdx.x;  // [0, NN*16)
    if (t >= NN * 16) return;
    int n = t >> 4;
    int q = t & 15;
    float w = dn[n];
    float4 a = reinterpret_cast<const float4*>(agg)[(size_t)n * 16 + q];
    float4 r;
    if (MODE == 0) {
        float4 h0 = (n < NU)
            ? reinterpret_cast<const float4*>(ue)[(size_t)n * 16 + q]
            : reinterpret_cast<const float4*>(ie)[(size_t)(n - NU) * 16 + q];
        r.x = h0.x + a.x * w; r.y = h0.y + a.y * w;
        r.z = h0.z + a.z * w; r.w = h0.w + a.w * w;
    } else {
        float4 c = reinterpret_cast<const float4*>(acc)[(size_t)n * 16 + q];
        r.x = c.x + a.x * w; r.y = c.y + a.y * w;
        r.z = c.z + a.z * w; r.w = c.w + a.w * w;
        if (MODE == 2) {
            r.x *= 0.25f; r.y *= 0.25f; r.z *= 0.25f; r.w *= 0.25f;
        }
    }
    reinterpret_cast<float4*>(acc)[(size_t)n * 16 + q] = r;
}

extern "C" void kernel_launch(void* const* d_in, const int* in_sizes, int n_in,
                              void* d_out, int out_size, void* d_ws, size_t ws_size,
                              hipStream_t stream) {
    const float* ue = (const float*)d_in[0];
    const float* ie = (const float*)d_in[1];
    const int*   src = (const int*)d_in[2];
    const int*   dst = (const int*)d_in[3];
    float* out = (float*)d_out;                 // acc lives here (NN*DIM f32)

    // workspace layout (floats):
    //   wsA [NN*DIM] | wsB [NN*DIM] | sn [NN] | dn [NN] | comb [NN]
    // total = 104.8M floats = 419.2 MB
    float* wsA  = (float*)d_ws;
    float* wsB  = wsA + (size_t)NN * DIM;
    float* sn   = wsB + (size_t)NN * DIM;
    float* dn   = sn + NN;
    float* comb = dn + NN;

    const size_t big = (size_t)NN * DIM * sizeof(float);

    // degrees + norms
    hipMemsetAsync(sn, 0, (size_t)2 * NN * sizeof(float), stream);  // sn,dn as deg accumulators
    deg_kernel<<<(NE + 255) / 256, 256, 0, stream>>>(src, dst, sn, dn);
    norm_kernel<<<(NN + 255) / 256, 256, 0, stream>>>(sn, dn, comb);

    const int eb = (NE * DIM + 255) / 256;  // 312500 blocks, 1 wave per edge
    const int pb = (NN * 16 + 255) / 256;   // 50000 blocks

    // layer 1: inputs -> wsA
    hipMemsetAsync(wsA, 0, big, stream);
    edge1_kernel<<<eb, 256, 0, stream>>>(ue, ie, src, dst, sn, wsA);
    p_kernel<0><<<pb, 256, 0, stream>>>(ue, ie, wsA, dn, out);

    // layer 2: wsA -> wsB
    hipMemsetAsync(wsB, 0, big, stream);
    edge_kernel<<<eb, 256, 0, stream>>>(wsA, src, dst, comb, wsB);
    p_kernel<1><<<pb, 256, 0, stream>>>(ue, ie, wsB, dn, out);

    // layer 3: wsB -> wsA
    hipMemsetAsync(wsA, 0, big, stream);
    edge_kernel<<<eb, 256, 0, stream>>>(wsB, src, dst, comb, wsA);
    p_kernel<2><<<pb, 256, 0, stream>>>(ue, ie, wsA, dn, out);
}

// Round 2
// 1401.661 us; speedup vs baseline: 1.2316x; 1.2316x over previous
//
#include <hip/hip_runtime.h>

// LightGCN on MI355X — CSR-by-dst gather formulation (no f32 atomics in layers).
// out = (h0 + (g1+g2+g3)*dn)/4, g1[v] = sum sn[s] h0[s], g_{k+1}[v] = sum comb[s] g_k[s].

static constexpr int NU = 500000;
static constexpr int NI = 300000;
static constexpr int NN = NU + NI;          // 800000
static constexpr int NE = 1250000;
static constexpr int DIM = 64;
static constexpr int CHUNK = 1024;          // elems per scan block (256 thr x 4)
static constexpr int NCHUNK = (NN + CHUNK - 1) / CHUNK;  // 782

// ---- int degree histogram ----
__global__ void hist_kernel(const int* __restrict__ src, const int* __restrict__ dst,
                            int* __restrict__ cout, int* __restrict__ cin) {
    int e = blockIdx.x * blockDim.x + threadIdx.x;
    if (e < NE) {
        atomicAdd(&cout[src[e]], 1);
        atomicAdd(&cin[dst[e]], 1);
    }
}

// ---- norms from int degrees ----
__global__ void norm_kernel(const int* __restrict__ cout, const int* __restrict__ cin,
                            float* __restrict__ sn, float* __restrict__ dn,
                            float* __restrict__ comb) {
    int i = blockIdx.x * blockDim.x + threadIdx.x;
    if (i < NN) {
        float a = rsqrtf(fmaxf((float)cout[i], 1.0f));
        float b = rsqrtf(fmaxf((float)cin[i], 1.0f));
        sn[i] = a; dn[i] = b; comb[i] = a * b;
    }
}

// ---- scan step 1: per-chunk sums ----
__global__ void scan_chunks(const int* __restrict__ cnt, int* __restrict__ chunkSum) {
    int b = blockIdx.x, t = threadIdx.x;
    int idx = b * CHUNK + t * 4;
    int s = 0;
    #pragma unroll
    for (int k = 0; k < 4; ++k) { int j = idx + k; if (j < NN) s += cnt[j]; }
    for (int off = 32; off; off >>= 1) s += __shfl_down(s, off);
    __shared__ int ws[4];
    if ((t & 63) == 0) ws[t >> 6] = s;
    __syncthreads();
    if (t == 0) chunkSum[b] = ws[0] + ws[1] + ws[2] + ws[3];
}

// ---- scan step 2: exclusive scan of chunk sums (1 block), in place ----
__global__ void scan_offsets(int* __restrict__ chunkSum) {
    int t = threadIdx.x;
    const int G = 4;                       // 256*4 = 1024 >= NCHUNK
    int loc[G]; int s = 0;
    #pragma unroll
    for (int k = 0; k < G; ++k) { int j = t * G + k; int v = (j < NCHUNK) ? chunkSum[j] : 0; loc[k] = s; s += v; }
    int ss = s;
    for (int off = 1; off < 64; off <<= 1) { int n = __shfl_up(ss, off); if ((t & 63) >= off) ss += n; }
    __shared__ int wtot[4];
    if ((t & 63) == 63) wtot[t >> 6] = ss;
    __syncthreads();
    int woff = 0;
    for (int w = 0; w < (t >> 6); ++w) woff += wtot[w];
    int excl = woff + ss - s;              // exclusive prefix for this thread
    #pragma unroll
    for (int k = 0; k < G; ++k) { int j = t * G + k; if (j < NCHUNK) chunkSum[j] = excl + loc[k]; }
}

// ---- scan step 3: fill cursor[i] = exclusive prefix (row start) ----
__global__ void scan_fill(const int* __restrict__ cnt, const int* __restrict__ chunkOff,
                          int* __restrict__ cursor) {
    int b = blockIdx.x, t = threadIdx.x;
    int idx = b * CHUNK + t * 4;
    int v[4]; int s = 0;
    #pragma unroll
    for (int k = 0; k < 4; ++k) { int j = idx + k; int c = (j < NN) ? cnt[j] : 0; v[k] = s; s += c; }
    int ss = s;
    for (int off = 1; off < 64; off <<= 1) { int n = __shfl_up(ss, off); if ((t & 63) >= off) ss += n; }
    __shared__ int wtot[4];
    if ((t & 63) == 63) wtot[t >> 6] = ss;
    __syncthreads();
    int woff = 0;
    for (int w = 0; w < (t >> 6); ++w) woff += wtot[w];
    int excl = woff + (ss - s) + chunkOff[b];
    #pragma unroll
    for (int k = 0; k < 4; ++k) { int j = idx + k; if (j < NN) cursor[j] = excl + v[k]; }
}

// ---- CSR scatter: after this, cursor[v] == row_end[v] ----
__global__ void scatter_kernel(const int* __restrict__ src, const int* __restrict__ dst,
                               int* __restrict__ cursor, int* __restrict__ eSrc) {
    int e = blockIdx.x * blockDim.x + threadIdx.x;
    if (e < NE) {
        int p = atomicAdd(&cursor[dst[e]], 1);
        eSrc[p] = src[e];
    }
}

// ---- layer kernels: one wave per node, lane = dim ----
// LAYER 1: gather from inputs, weight sn   -> writes g1
// LAYER 2: gather from g,      weight comb -> writes g2
// LAYER 3: gather from g,      weight comb -> fused epilogue writes final out
template <int LAYER>
__global__ void layer_kernel(const float* __restrict__ ue, const float* __restrict__ ie,
                             const float* __restrict__ g,    // prev g (unused LAYER 1)
                             const int* __restrict__ cursor, const int* __restrict__ eSrc,
                             const float* __restrict__ sn, const float* __restrict__ dn,
                             const float* __restrict__ comb,
                             const float* __restrict__ g1,   // only LAYER 3
                             float* __restrict__ outbuf) {
    int t = blockIdx.x * blockDim.x + threadIdx.x;
    int v = t >> 6;
    if (v >= NN) return;
    int d = t & 63;
    int end = cursor[v];
    int start = (v == 0) ? 0 : cursor[v - 1];
    float acc = 0.0f;
    for (int i = start; i < end; ++i) {
        int s = eSrc[i];                    // wave-uniform
        float w, hv;
        if (LAYER == 1) {
            w = sn[s];
            hv = (s < NU) ? ue[(size_t)s * DIM + d] : ie[(size_t)(s - NU) * DIM + d];
        } else {
            w = comb[s];
            hv = g[(size_t)s * DIM + d];
        }
        acc = fmaf(w, hv, acc);
    }
    if (LAYER < 3) {
        outbuf[(size_t)v * DIM + d] = acc;
    } else {
        float h0 = (v < NU) ? ue[(size_t)v * DIM + d] : ie[(size_t)(v - NU) * DIM + d];
        float gs = g1[(size_t)v * DIM + d] + g[(size_t)v * DIM + d] + acc;
        outbuf[(size_t)v * DIM + d] = 0.25f * (h0 + gs * dn[v]);
    }
}

extern "C" void kernel_launch(void* const* d_in, const int* in_sizes, int n_in,
                              void* d_out, int out_size, void* d_ws, size_t ws_size,
                              hipStream_t stream) {
    const float* ue = (const float*)d_in[0];
    const float* ie = (const float*)d_in[1];
    const int* src = (const int*)d_in[2];
    const int* dst = (const int*)d_in[3];
    float* out = (float*)d_out;            // doubles as g1 storage

    // ws layout (4B units):
    //   cout[NN] cin[NN] cursor[NN] chunkSum[1024] eSrc[NE] sn[NN] dn[NN] comb[NN] g2[NN*DIM]
    int* cout = (int*)d_ws;
    int* cin = cout + NN;
    int* cursor = cin + NN;
    int* chunkSum = cursor + NN;
    int* eSrc = chunkSum + 1024;
    float* sn = (float*)(eSrc + NE);
    float* dn = sn + NN;
    float* comb = dn + NN;
    float* g2 = comb + NN;

    const int EB = (NE + 255) / 256;        // edge-parallel blocks
    const int NB = (NN + 255) / 256;        // node-parallel blocks
    const int LB = (NN * 64 + 255) / 256;   // wave-per-node blocks (200000)

    // degrees + norms + CSR build
    hipMemsetAsync(cout, 0, (size_t)2 * NN * sizeof(int), stream);
    hist_kernel<<<EB, 256, 0, stream>>>(src, dst, cout, cin);
    norm_kernel<<<NB, 256, 0, stream>>>(cout, cin, sn, dn, comb);
    scan_chunks<<<NCHUNK, 256, 0, stream>>>(cin, chunkSum);
    scan_offsets<<<1, 256, 0, stream>>>(chunkSum);
    scan_fill<<<NCHUNK, 256, 0, stream>>>(cin, chunkSum, cursor);
    scatter_kernel<<<EB, 256, 0, stream>>>(src, dst, cursor, eSrc);
    // cursor[v] is now row_end[v]

    // layer 1: inputs -> g1 (stored in out)
    layer_kernel<1><<<LB, 256, 0, stream>>>(ue, ie, nullptr, cursor, eSrc, sn, dn, comb, nullptr, out);
    // layer 2: g1 -> g2
    layer_kernel<2><<<LB, 256, 0, stream>>>(ue, ie, out, cursor, eSrc, sn, dn, comb, nullptr, g2);
    // layer 3: g2 -> g3, fused final: out = 0.25*(h0 + (g1+g2+g3)*dn)
    layer_kernel<3><<<LB, 256, 0, stream>>>(ue, ie, g2, cursor, eSrc, sn, dn, comb, out, out);
}

// Round 4
// 1318.766 us; speedup vs baseline: 1.3091x; 1.0629x over previous
//
#include <hip/hip_runtime.h>
#include <hip/hip_fp16.h>

// LightGCN on MI355X — CSR gather + fp16 message buffers (L3-resident working set).
// m_k = sn ⊙ h_k stored fp16; m_{k+1} = comb ⊙ (A m_k); h_k = m_k / sn.
// out = 0.25 * (h0 + (m1+m2)*rn + dn*agg3),  rn = 1/sn.
// (Resubmission of round-3 kernel — previous bench died to container failure,
//  not a kernel error.)

static constexpr int NU = 500000;
static constexpr int NI = 300000;
static constexpr int NN = NU + NI;          // 800000
static constexpr int NE = 1250000;
static constexpr int DIM = 64;
static constexpr int CHUNK = 1024;
static constexpr int NCHUNK = (NN + CHUNK - 1) / CHUNK;  // 782

// ---- int degree histogram ----
__global__ void hist_kernel(const int* __restrict__ src, const int* __restrict__ dst,
                            int* __restrict__ cout, int* __restrict__ cin) {
    int e = blockIdx.x * blockDim.x + threadIdx.x;
    if (e < NE) {
        atomicAdd(&cout[src[e]], 1);
        atomicAdd(&cin[dst[e]], 1);
    }
}

// ---- norms from int degrees ----
__global__ void norm_kernel(const int* __restrict__ cout, const int* __restrict__ cin,
                            float* __restrict__ sn, float* __restrict__ dn,
                            float* __restrict__ comb, float* __restrict__ rn) {
    int i = blockIdx.x * blockDim.x + threadIdx.x;
    if (i < NN) {
        float fo = fmaxf((float)cout[i], 1.0f);
        float a = rsqrtf(fo);
        float b = rsqrtf(fmaxf((float)cin[i], 1.0f));
        sn[i] = a; dn[i] = b; comb[i] = a * b; rn[i] = sqrtf(fo);
    }
}

// ---- scan step 1: per-chunk sums ----
__global__ void scan_chunks(const int* __restrict__ cnt, int* __restrict__ chunkSum) {
    int b = blockIdx.x, t = threadIdx.x;
    int idx = b * CHUNK + t * 4;
    int s = 0;
    #pragma unroll
    for (int k = 0; k < 4; ++k) { int j = idx + k; if (j < NN) s += cnt[j]; }
    for (int off = 32; off; off >>= 1) s += __shfl_down(s, off);
    __shared__ int ws[4];
    if ((t & 63) == 0) ws[t >> 6] = s;
    __syncthreads();
    if (t == 0) chunkSum[b] = ws[0] + ws[1] + ws[2] + ws[3];
}

// ---- scan step 2: exclusive scan of chunk sums (1 block), in place ----
__global__ void scan_offsets(int* __restrict__ chunkSum) {
    int t = threadIdx.x;
    const int G = 4;
    int loc[G]; int s = 0;
    #pragma unroll
    for (int k = 0; k < G; ++k) { int j = t * G + k; int v = (j < NCHUNK) ? chunkSum[j] : 0; loc[k] = s; s += v; }
    int ss = s;
    for (int off = 1; off < 64; off <<= 1) { int n = __shfl_up(ss, off); if ((t & 63) >= off) ss += n; }
    __shared__ int wtot[4];
    if ((t & 63) == 63) wtot[t >> 6] = ss;
    __syncthreads();
    int woff = 0;
    for (int w = 0; w < (t >> 6); ++w) woff += wtot[w];
    int excl = woff + ss - s;
    #pragma unroll
    for (int k = 0; k < G; ++k) { int j = t * G + k; if (j < NCHUNK) chunkSum[j] = excl + loc[k]; }
}

// ---- scan step 3: cursor[i] = row start ----
__global__ void scan_fill(const int* __restrict__ cnt, const int* __restrict__ chunkOff,
                          int* __restrict__ cursor) {
    int b = blockIdx.x, t = threadIdx.x;
    int idx = b * CHUNK + t * 4;
    int v[4]; int s = 0;
    #pragma unroll
    for (int k = 0; k < 4; ++k) { int j = idx + k; int c = (j < NN) ? cnt[j] : 0; v[k] = s; s += c; }
    int ss = s;
    for (int off = 1; off < 64; off <<= 1) { int n = __shfl_up(ss, off); if ((t & 63) >= off) ss += n; }
    __shared__ int wtot[4];
    if ((t & 63) == 63) wtot[t >> 6] = ss;
    __syncthreads();
    int woff = 0;
    for (int w = 0; w < (t >> 6); ++w) woff += wtot[w];
    int excl = woff + (ss - s) + chunkOff[b];
    #pragma unroll
    for (int k = 0; k < 4; ++k) { int j = idx + k; if (j < NN) cursor[j] = excl + v[k]; }
}

// ---- CSR scatter: after this, cursor[v] == row_end[v] ----
__global__ void scatter_kernel(const int* __restrict__ src, const int* __restrict__ dst,
                               int* __restrict__ cursor, int* __restrict__ eSrc) {
    int e = blockIdx.x * blockDim.x + threadIdx.x;
    if (e < NE) {
        int p = atomicAdd(&cursor[dst[e]], 1);
        eSrc[p] = src[e];
    }
}

// ---- prep: m0 = sn ⊙ h0, fp16 ----
__global__ void prep_kernel(const float* __restrict__ ue, const float* __restrict__ ie,
                            const float* __restrict__ sn, __half* __restrict__ m0) {
    int t = blockIdx.x * blockDim.x + threadIdx.x;   // [0, NN*16)
    if (t >= NN * 16) return;
    int n = t >> 4; int q = t & 15;
    float w = sn[n];
    float4 h = (n < NU) ? reinterpret_cast<const float4*>(ue)[(size_t)n * 16 + q]
                        : reinterpret_cast<const float4*>(ie)[(size_t)(n - NU) * 16 + q];
    __half2 a = __floats2half2_rn(w * h.x, w * h.y);
    __half2 b = __floats2half2_rn(w * h.z, w * h.w);
    reinterpret_cast<__half2*>(m0)[(size_t)t * 2]     = a;
    reinterpret_cast<__half2*>(m0)[(size_t)t * 2 + 1] = b;
}

// ---- layer kernels: one wave per node, lane = dim ----
// LAYER 1/2: gather m_in, write m_out = comb[v]*agg (fp16)
// LAYER 3:   gather m_in, fused epilogue -> f32 out
template <int LAYER>
__global__ void layer_kernel(const __half* __restrict__ min_,
                             const int* __restrict__ rowend, const int* __restrict__ eSrc,
                             const float* __restrict__ comb, __half* __restrict__ mout,
                             const __half* __restrict__ m1, const __half* __restrict__ m2,
                             const float* __restrict__ rn, const float* __restrict__ dn,
                             const float* __restrict__ ue, const float* __restrict__ ie,
                             float* __restrict__ out) {
    int t = blockIdx.x * blockDim.x + threadIdx.x;
    int v = t >> 6;
    if (v >= NN) return;
    int d = t & 63;
    int end = rowend[v];
    int start = (v == 0) ? 0 : rowend[v - 1];
    float acc = 0.0f;
    for (int i = start; i < end; ++i) {
        int s = eSrc[i];                              // wave-uniform
        acc += __half2float(min_[(size_t)s * DIM + d]);
    }
    size_t idx = (size_t)v * DIM + d;
    if (LAYER < 3) {
        mout[idx] = __float2half(comb[v] * acc);
    } else {
        float h0 = (v < NU) ? ue[idx] : ie[idx - (size_t)NU * DIM];
        float ms = __half2float(m1[idx]) + __half2float(m2[idx]);
        out[idx] = 0.25f * (h0 + ms * rn[v] + dn[v] * acc);
    }
}

extern "C" void kernel_launch(void* const* d_in, const int* in_sizes, int n_in,
                              void* d_out, int out_size, void* d_ws, size_t ws_size,
                              hipStream_t stream) {
    const float* ue = (const float*)d_in[0];
    const float* ie = (const float*)d_in[1];
    const int* src = (const int*)d_in[2];
    const int* dst = (const int*)d_in[3];
    float* out = (float*)d_out;

    // ws layout (4B units):
    //   cout[NN] cin[NN] cursor[NN] chunkSum[1024] eSrc[NE] sn dn comb rn [NN each]
    //   m0 m1 m2 [NN*DIM halves = NN*32 ints each]
    int* cout = (int*)d_ws;
    int* cin = cout + NN;
    int* cursor = cin + NN;
    int* chunkSum = cursor + NN;
    int* eSrc = chunkSum + 1024;
    float* sn = (float*)(eSrc + NE);
    float* dn = sn + NN;
    float* comb = dn + NN;
    float* rn = comb + NN;
    __half* m0 = (__half*)(rn + NN);
    __half* m1 = m0 + (size_t)NN * DIM;
    __half* m2 = m1 + (size_t)NN * DIM;

    const int EB = (NE + 255) / 256;
    const int NB = (NN + 255) / 256;
    const int PB = (NN * 16 + 255) / 256;    // prep
    const int LB = (NN * 64 + 255) / 256;    // wave-per-node

    // degrees + norms + CSR build
    hipMemsetAsync(cout, 0, (size_t)2 * NN * sizeof(int), stream);
    hist_kernel<<<EB, 256, 0, stream>>>(src, dst, cout, cin);
    norm_kernel<<<NB, 256, 0, stream>>>(cout, cin, sn, dn, comb, rn);
    scan_chunks<<<NCHUNK, 256, 0, stream>>>(cin, chunkSum);
    scan_offsets<<<1, 256, 0, stream>>>(chunkSum);
    scan_fill<<<NCHUNK, 256, 0, stream>>>(cin, chunkSum, cursor);
    scatter_kernel<<<EB, 256, 0, stream>>>(src, dst, cursor, eSrc);
    // cursor[v] is now row_end[v]

    // m0 = sn ⊙ h0
    prep_kernel<<<PB, 256, 0, stream>>>(ue, ie, sn, m0);

    // layers
    layer_kernel<1><<<LB, 256, 0, stream>>>(m0, cursor, eSrc, comb, m1,
                                            nullptr, nullptr, rn, dn, ue, ie, out);
    layer_kernel<2><<<LB, 256, 0, stream>>>(m1, cursor, eSrc, comb, m2,
                                            nullptr, nullptr, rn, dn, ue, ie, out);
    layer_kernel<3><<<LB, 256, 0, stream>>>(m2, cursor, eSrc, comb, nullptr,
                                            m1, m2, rn, dn, ue, ie, out);
}